// Round 2
// baseline (21152.859 us; speedup 1.0000x reference)
//
#include <hip/hip_runtime.h>
#include <hip/hip_bf16.h>
#include <stdint.h>

typedef __hip_bfloat16 bf16;

// Problem constants: B=8, C=128, H=W=256, J=19, D=64, NH=128
// All float tensors are fp32 (per reference). Output fp32.
// ws layout (float offsets)
#define OFF_NZT   0          // [8][256][256] transposed noise (fp32)
#define OFF_MU    524288     // [8][19][64]
#define OFF_MEAN  534016     // [1024]
#define OFF_RSTD  535040     // [1024]
#define OFF_WC    536064     // [16][19][128] collapsed conv1 weights
#define OFF_GG    574976     // [8][20][9][128] gamma_avg tables (row 19 = zeros)
#define OFF_GB    759296     // [8][20][9][128]
#define OFF_W2GT  943616     // [128][9][128] spade_gamma_w transposed
#define OFF_W2BT  1091072    // [128][9][128]
#define OFF_BITS  1238528    // [8][128][128] uint32 class bitmasks
// total = 1369600 floats = 5,478,400 bytes of ws

// ---------------- K0: transpose noise (B,W,H,1) -> fp32 [b][h][w] ----------------
__global__ void k_nzT(const float* __restrict__ noise, float* __restrict__ nzT){
    int i = blockIdx.x*256 + threadIdx.x;          // 524288
    int b = i >> 16, r = i & 65535;
    int h = r >> 8, w = r & 255;
    nzT[i] = noise[(b<<16) + (w<<8) + h];
}

// ---------------- K1: mu[b][j][o] = relu(fc_b + fc_w @ style) ----------------
__global__ void k_mu(const float* __restrict__ style, const float* __restrict__ fcw,
                     const float* __restrict__ fcb, float* __restrict__ mu){
    int blk = blockIdx.x;            // 152 = 8*19
    int b = blk / 19, j = blk % 19;
    int o = threadIdx.x;             // 64
    const float* wr = fcw + (j*64 + o)*64;
    const float* sr = style + (b*19 + j)*64;
    float acc = fcb[j*64 + o];
    for (int i = 0; i < 64; i++) acc = fmaf(wr[i], sr[i], acc);
    mu[(b*19 + j)*64 + o] = fmaxf(acc, 0.f);
}

// ---------------- K2: instance-norm stats over (x + noise*nv) ----------------
__global__ void k_stats(const float* __restrict__ x, const float* __restrict__ nzT,
                        const float* __restrict__ nvar, float* __restrict__ meanv,
                        float* __restrict__ rstdv){
    int bc = blockIdx.x;             // 1024
    int b = bc >> 7, c = bc & 127;
    float nv = nvar[c];
    const float* xp  = x   + ((size_t)bc << 16);
    const float* np_ = nzT + ((size_t)b  << 16);
    float s1 = 0.f, s2 = 0.f;
    for (int k = 0; k < 256; k++){
        int idx = (k << 8) + threadIdx.x;
        float v = xp[idx] + nv * np_[idx];
        s1 += v; s2 = fmaf(v, v, s2);
    }
    for (int o = 32; o > 0; o >>= 1){ s1 += __shfl_down(s1, o, 64); s2 += __shfl_down(s2, o, 64); }
    __shared__ float r1[4], r2[4];
    int wid = threadIdx.x >> 6;
    if ((threadIdx.x & 63) == 0){ r1[wid] = s1; r2[wid] = s2; }
    __syncthreads();
    if (threadIdx.x == 0){
        float t1 = r1[0]+r1[1]+r1[2]+r1[3];
        float t2 = r2[0]+r2[1]+r2[2]+r2[3];
        float m = t1 * (1.f/65536.f);
        float var = t2 * (1.f/65536.f) - m*m;
        meanv[bc] = m;
        rstdv[bc] = rsqrtf(var + 1e-5f);
    }
}

// ---------------- K3: collapsed conv1 weights Wc[rs][j][n] ----------------
__global__ void k_wc(const float* __restrict__ w1, float* __restrict__ wc){
    int rs = blockIdx.x;             // 16
    int n  = threadIdx.x;            // 128
    int ry = (rs>>3)&1, rx = (rs>>2)&1, sy = (rs>>1)&1, sx = rs&1;
    for (int j = 0; j < 19; j++){
        float acc = 0.f;
        for (int dy = 0; dy < 3; dy++){
            bool iy = (ry==0) ? (sy==0 ? (dy==0) : (dy>=1)) : (sy==0 ? (dy<=1) : (dy==2));
            if (!iy) continue;
            for (int dx = 0; dx < 3; dx++){
                bool ix = (rx==0) ? (sx==0 ? (dx==0) : (dx>=1)) : (sx==0 ? (dx<=1) : (dx==2));
                if (ix) acc += w1[(n*19 + j)*9 + dy*3 + dx];
            }
        }
        wc[(rs*19 + j)*128 + n] = acc;
    }
}

// ---------------- K4: G tables (avg branch collapsed to per-class rows) ----------------
__global__ void k_gtab(const float* __restrict__ cgw, const float* __restrict__ cbw,
                       const float* __restrict__ mu, float* __restrict__ Gg,
                       float* __restrict__ Gb){
    int t = blockIdx.x;              // 9
    int j = blockIdx.y;              // 20 (19 = zero row for "uncovered")
    int b = blockIdx.z;              // 8
    int c = threadIdx.x;             // 128
    float ag = 0.f, ab = 0.f;
    if (j < 19){
        const float* mup = mu + (b*19 + j)*64;
        const float* wg = cgw + (size_t)c*576 + t;   // (c*64+d)*9+t
        const float* wb = cbw + (size_t)c*576 + t;
        for (int d = 0; d < 64; d++){
            float mv = mup[d];
            ag = fmaf(wg[d*9], mv, ag);
            ab = fmaf(wb[d*9], mv, ab);
        }
    }
    int o = ((b*20 + j)*9 + t)*128 + c;
    Gg[o] = ag; Gb[o] = ab;
}

// ---------------- K5: class bitmasks at half-res ----------------
__global__ void k_bits(const float* __restrict__ segmap, unsigned* __restrict__ bits){
    int i = blockIdx.x*256 + threadIdx.x;    // 131072
    int b = i >> 14, q = i & 16383;
    unsigned m = 0;
    for (int j = 0; j < 19; j++)
        if (segmap[((size_t)(b*19 + j) << 14) + q] > 0.f) m |= (1u << j);
    bits[i] = m;
}

// ---------------- K5b: transpose conv2 weights to [c][t][n] ----------------
__global__ void k_w2t(const float* __restrict__ sgw, const float* __restrict__ sbw,
                      float* __restrict__ w2gT, float* __restrict__ w2bT){
    int t = blockIdx.x, c = blockIdx.y, br = blockIdx.z;
    int n = threadIdx.x;             // 128
    const float* src = br ? sbw : sgw;
    float* dst = br ? w2bT : w2gT;
    dst[(c*9 + t)*128 + n] = src[((size_t)(c*128 + n))*9 + t];
}

// ---------------- K6: fused final ----------------
// 16x8 pixel tile per block, 128 threads.
__global__ __launch_bounds__(128) void kf_final(
    const float* __restrict__ x, const float* __restrict__ nvar,
    const float* __restrict__ bgam, const float* __restrict__ bbet,
    const float* __restrict__ cgb, const float* __restrict__ cbb,
    const float* __restrict__ ssb, const float* __restrict__ sgb,
    const float* __restrict__ sbb,
    const float* __restrict__ ws, const unsigned* __restrict__ bitsws,
    float* __restrict__ out)
{
    const float* wsWc  = ws + OFF_WC;
    const float* wsGg  = ws + OFF_GG;
    const float* wsGb  = ws + OFF_GB;
    const float* w2gT  = ws + OFF_W2GT;
    const float* w2bT  = ws + OFF_W2BT;
    const float* nzT   = ws + OFF_NZT;
    const float* meanv = ws + OFF_MEAN;
    const float* rstdv = ws + OFF_RSTD;

    const int gx = blockIdx.x;   // 16 tiles of 16 px wide
    const int gy = blockIdx.y;   // 32 tiles of 8 px tall
    const int b  = blockIdx.z;
    const int tid = threadIdx.x;

    __shared__ unsigned segb[60];          // 6 rows x 10 cols of half-res bitmasks
    __shared__ bf16 actvL[10*18*128];      // halo actv tile, channels-last

    // Phase A
    if (tid < 60){
        int ly = tid / 10, lx = tid % 10;
        int qy = 4*gy - 1 + ly, qx = 8*gx - 1 + lx;
        unsigned m = 0;
        if (qy >= 0 && qy < 128 && qx >= 0 && qx < 128)
            m = bitsws[(b<<14) + (qy<<7) + qx];
        segb[tid] = m;
    }
    __syncthreads();

    // Phase B: thread = channel n; loop spatial (wave-uniform bitmask per sp)
    {
        const int n = tid;
        const float bias = ssb[n];
        int ay = 0, ax = 0;
        for (int sp = 0; sp < 180; sp++){
            int a_y = 8*gy - 1 + ay;
            int a_x = 16*gx - 1 + ax;
            float res = 0.f;
            if (a_y >= 0 && a_y < 256 && a_x >= 0 && a_x < 256){
                int ry = a_y & 1, rx = a_x & 1;
                int uy = a_y >> 1, ux = a_x >> 1;
                float acc = bias;
                #pragma unroll
                for (int sy = 0; sy < 2; sy++){
                    int ly = uy + sy - 1 + ry - (4*gy - 1);
                    #pragma unroll
                    for (int sx = 0; sx < 2; sx++){
                        int lx = ux + sx - 1 + rx - (8*gx - 1);
                        unsigned m = segb[ly*10 + lx];
                        m = __builtin_amdgcn_readfirstlane(m);  // wave-uniform
                        const float* wrow = wsWc + (((ry*2+rx)*2+sy)*2+sx)*19*128 + n;
                        while (m){
                            int j = __builtin_ctz(m);
                            acc += wrow[j << 7];
                            m &= m - 1;
                        }
                    }
                }
                res = fmaxf(acc, 0.f);
            }
            actvL[(sp << 7) + n] = __float2bfloat16(res);
            if (++ax == 18){ ax = 0; ++ay; }
        }
    }
    __syncthreads();

    // Phase C: thread = pixel
    const int tpy = tid >> 4, tpx = tid & 15;
    const int py = 8*gy + tpy, px = 16*gx + tpx;

    int goff[9];
    #pragma unroll
    for (int t = 0; t < 9; t++){
        int ey = tpy + (t/3) - 1, ex = tpx + (t%3) - 1;
        unsigned m = segb[((ey>>1)+1)*10 + ((ex>>1)+1)];
        int lbl = m ? (31 - __builtin_clz(m)) : 19;
        goff[t] = ((lbl*9 + t) << 7);
    }
    const float* GgB = wsGg + b*23040;   // 20*9*128
    const float* GbB = wsGb + b*23040;
    const float nz = nzT[(b<<16) + (py<<8) + px];
    const float ga = 1.f/(1.f + __expf(-bgam[0]));
    const float ba = 1.f/(1.f + __expf(-bbet[0]));
    const int xbase = b*8388608 + (py<<8) + px;   // b*C*H*W + py*W + px

    #pragma unroll 1
    for (int cc = 0; cc < 128; cc += 8){
        float agx[8], agy[8], abx[8], aby[8];
        #pragma unroll
        for (int i = 0; i < 8; i++){ agx[i]=0.f; agy[i]=0.f; abx[i]=0.f; aby[i]=0.f; }

        #pragma unroll 1
        for (int dy = 0; dy < 3; dy++){
            #pragma unroll 1
            for (int dx = 0; dx < 3; dx++){
                const int t = dy*3 + dx;
                const uint2* av = (const uint2*)&actvL[(((tpy+dy)*18 + (tpx+dx)) << 7)];
                const float* wg0 = w2gT + cc*1152 + (t << 7);
                const float* wb0 = w2bT + cc*1152 + (t << 7);
                for (int n4 = 0; n4 < 32; n4++){
                    uint2 u = av[n4];
                    float a0 = __uint_as_float(u.x << 16);
                    float a1 = __uint_as_float(u.x & 0xffff0000u);
                    float a2 = __uint_as_float(u.y << 16);
                    float a3 = __uint_as_float(u.y & 0xffff0000u);
                    #pragma unroll
                    for (int i = 0; i < 8; i++){
                        const float4 wg = *(const float4*)(wg0 + i*1152 + (n4<<2));
                        agx[i] = fmaf(a0, wg.x, agx[i]);
                        agy[i] = fmaf(a1, wg.y, agy[i]);
                        agx[i] = fmaf(a2, wg.z, agx[i]);
                        agy[i] = fmaf(a3, wg.w, agy[i]);
                    }
                    #pragma unroll
                    for (int i = 0; i < 8; i++){
                        const float4 wb = *(const float4*)(wb0 + i*1152 + (n4<<2));
                        abx[i] = fmaf(a0, wb.x, abx[i]);
                        aby[i] = fmaf(a1, wb.y, aby[i]);
                        abx[i] = fmaf(a2, wb.z, abx[i]);
                        aby[i] = fmaf(a3, wb.w, aby[i]);
                    }
                }
            }
        }

        #pragma unroll
        for (int i = 0; i < 8; i++){
            const int c = cc + i;
            float gavg = cgb[c];
            float bavg = cbb[c];
            #pragma unroll
            for (int t = 0; t < 9; t++){
                gavg += GgB[goff[t] + c];
                bavg += GbB[goff[t] + c];
            }
            const float gs = agx[i] + agy[i] + sgb[c];
            const float bs = abx[i] + aby[i] + sbb[c];
            const float gf  = ga*gavg + (1.f - ga)*gs;
            const float bfv = ba*bavg + (1.f - ba)*bs;
            const int xi = xbase + (c << 16);
            const float v = x[xi] + nvar[c]*nz;
            const float nrm = (v - meanv[(b<<7) + c]) * rstdv[(b<<7) + c];
            out[xi] = nrm*(1.f + gf) + bfv;
        }
    }
}

extern "C" void kernel_launch(void* const* d_in, const int* in_sizes, int n_in,
                              void* d_out, int out_size, void* d_ws, size_t ws_size,
                              hipStream_t stream) {
    const float* x     = (const float*)d_in[0];
    const float* seg   = (const float*)d_in[1];
    const float* style = (const float*)d_in[2];
    const float* noise = (const float*)d_in[3];
    const float* nvar  = (const float*)d_in[4];
    const float* bgam  = (const float*)d_in[5];
    const float* bbet  = (const float*)d_in[6];
    const float* fcw   = (const float*)d_in[7];
    const float* fcb   = (const float*)d_in[8];
    const float* cgw   = (const float*)d_in[9];
    const float* cgb   = (const float*)d_in[10];
    const float* cbw   = (const float*)d_in[11];
    const float* cbb   = (const float*)d_in[12];
    const float* ssw   = (const float*)d_in[13];
    const float* ssb   = (const float*)d_in[14];
    const float* sgw   = (const float*)d_in[15];
    const float* sgb   = (const float*)d_in[16];
    const float* sbw   = (const float*)d_in[17];
    const float* sbb   = (const float*)d_in[18];
    float* out = (float*)d_out;

    float* ws = (float*)d_ws;
    unsigned* bits = (unsigned*)(ws + OFF_BITS);

    k_nzT  <<<2048, 256, 0, stream>>>(noise, ws + OFF_NZT);
    k_mu   <<<152,  64,  0, stream>>>(style, fcw, fcb, ws + OFF_MU);
    k_stats<<<1024, 256, 0, stream>>>(x, ws + OFF_NZT, nvar, ws + OFF_MEAN, ws + OFF_RSTD);
    k_wc   <<<16,   128, 0, stream>>>(ssw, ws + OFF_WC);
    k_gtab <<<dim3(9,20,8), 128, 0, stream>>>(cgw, cbw, ws + OFF_MU, ws + OFF_GG, ws + OFF_GB);
    k_bits <<<512,  256, 0, stream>>>(seg, bits);
    k_w2t  <<<dim3(9,128,2), 128, 0, stream>>>(sgw, sbw, ws + OFF_W2GT, ws + OFF_W2BT);
    kf_final<<<dim3(16,32,8), 128, 0, stream>>>(x, nvar, bgam, bbet, cgb, cbb,
                                                ssb, sgb, sbb, ws, bits, out);
}